// Round 5
// baseline (2360.700 us; speedup 1.0000x reference)
//
#include <hip/hip_runtime.h>
#include <hip/hip_cooperative_groups.h>
namespace cg = cooperative_groups;

// Problem constants
#define BB 64
#define TT 4
#define NOBJ 6
#define RTOT 1536   // B*T*N
#define DD 256

typedef unsigned short ushort_t;
typedef __attribute__((ext_vector_type(8))) short short8_t;   // 8 bf16 (4 VGPRs)
typedef __attribute__((ext_vector_type(4))) float f32x4;

struct MatDesc { const float* src; float* dst; int kshift; int stride; int coff; };
struct MatDescs { MatDesc m[28]; };

#define FMA4(ACC, A4, W4) do { \
  ACC = fmaf((A4).x, (W4).x, ACC); \
  ACC = fmaf((A4).y, (W4).y, ACC); \
  ACC = fmaf((A4).z, (W4).z, ACC); \
  ACC = fmaf((A4).w, (W4).w, ACC); } while(0)

// ---- prep: transpose N=256 weight mats into WT[kq][d][4] layout ----
__global__ void prep_mats(MatDescs md) {
  const MatDesc de = md.m[blockIdx.y];
  int K = 1 << de.kshift;
  int idx = blockIdx.x * 256 + threadIdx.x;
  if (idx >= (256 << de.kshift)) return;
  int d = idx >> de.kshift;
  int kk = idx & (K - 1);
  de.dst[(kk >> 2) * 1024 + d * 4 + (kk & 3)] = de.src[d * de.stride + de.coff + kk];
}

// ---- prep: w1p[tap*64+co], w2 split-bf16 planes, rbuf ----
__global__ void prep_small(const float* __restrict__ w1, const float* __restrict__ w2,
                           const float* __restrict__ rois, float* __restrict__ w1p,
                           ushort_t* __restrict__ w2fh, ushort_t* __restrict__ w2fl,
                           float* __restrict__ rbuf) {
  int idx = blockIdx.x * 256 + threadIdx.x;
  if (idx < 1728) w1p[idx] = w1[(idx & 63) * 27 + (idx >> 6)];
  int i2 = idx - 2048;
  if (i2 >= 0 && i2 < 36864) {
    int j = i2 & 7, lane = (i2 >> 3) & 63, nt = (i2 >> 9) & 3, q = (i2 >> 11) & 1, t = i2 >> 12;
    int co = nt * 16 + (lane & 15);
    int ci = q * 32 + ((lane >> 4) << 3) + j;
    float v = w2[(co * 64 + ci) * 9 + t];
    unsigned int b = __float_as_uint(v);
    w2fh[i2] = (ushort_t)(b >> 16);
    float hf = __uint_as_float(b & 0xFFFF0000u);
    w2fl[i2] = (ushort_t)(__float_as_uint(v - hf) >> 16);
  }
  int i3 = idx - 38912;
  if (i3 >= 0 && i3 < 384) {
    int b = i3 / 6, n = i3 % 6;
    float acc = 0.f;
    for (int t = 0; t < TT; t++) {
      const float* rp = rois + ((b * TT + t) * NOBJ + n) * 5;
      acc += (rp[4] - rp[2]) * 0.5f + (rp[3] - rp[1]) * 0.5f;
    }
    rbuf[i3] = acc * 0.125f;
  }
}

// ---- conv1: x -> relu conv1 s2 -> f1 split-bf16 planes [nl][row65][col65][ch64] ----
// grid 256 per batch: block = (nl, quarter). wave = ch-octet, lane = col 0..63.
__global__ __launch_bounds__(512, 4) void conv1_kernel(const float* __restrict__ x,
                                                       const float* __restrict__ w1p,
                                                       const float* __restrict__ b1,
                                                       ushort_t* __restrict__ f1h,
                                                       ushort_t* __restrict__ f1l, int n0) {
  __shared__ float w1s[1728];
  __shared__ float b1s[64];
  int bx = blockIdx.x;
  int qd = bx & 3;
  int nl = bx >> 2;
  int n = n0 + nl;
  int tid = threadIdx.x;
  for (int i = tid; i < 1728; i += 512) w1s[i] = w1p[i];
  if (tid < 64) b1s[tid] = b1[tid];
  __syncthreads();
  int wave = __builtin_amdgcn_readfirstlane(tid >> 6);
  int c = tid & 63;
  int chb = wave * 8;
  float bb[8];
  #pragma unroll
  for (int j = 0; j < 8; j++) bb[j] = b1s[chb + j];
  size_t fbase = (size_t)nl * 270400;
  const float* xn = x + (size_t)n * 3 * 128 * 128;
  int y0q = qd * 16;
  for (int ch = 0; ch < 2; ch++) {
    int y0 = y0q + ch * 8;
    float acc[8][8] = {};
    for (int ci = 0; ci < 3; ci++) {
      #pragma unroll
      for (int ky = 0; ky < 3; ky++) {
        const float* wp = &w1s[((ci * 3 + ky) * 3) * 64 + chb];
        float wv[3][8];
        #pragma unroll
        for (int kx = 0; kx < 3; kx++)
          #pragma unroll
          for (int j = 0; j < 8; j++) wv[kx][j] = wp[kx * 64 + j];
        #pragma unroll
        for (int yy = 0; yy < 8; yy++) {
          int row = 2 * (y0 + yy) + ky;
          const float* xp = xn + (ci * 128 + row) * 128 + 2 * c;
          float x0 = 0.f, x1v = 0.f, x2v = 0.f;
          if (row < 128) {
            float2 v2 = *(const float2*)xp;
            x0 = v2.x; x1v = v2.y;
            if (c < 63) x2v = xp[2];
          }
          #pragma unroll
          for (int j = 0; j < 8; j++) {
            acc[yy][j] = fmaf(x0, wv[0][j], acc[yy][j]);
            acc[yy][j] = fmaf(x1v, wv[1][j], acc[yy][j]);
            acc[yy][j] = fmaf(x2v, wv[2][j], acc[yy][j]);
          }
        }
      }
    }
    #pragma unroll
    for (int yy = 0; yy < 8; yy++) {
      int y = y0 + yy;
      short8_t hv, lv;
      #pragma unroll
      for (int j = 0; j < 8; j++) {
        float v = fmaxf(acc[yy][j] + bb[j], 0.f);
        unsigned int bits = __float_as_uint(v);
        hv[j] = (short)(bits >> 16);
        float hf = __uint_as_float(bits & 0xFFFF0000u);
        lv[j] = (short)(__float_as_uint(v - hf) >> 16);
      }
      size_t off = fbase + (size_t)y * 4160 + c * 64 + chb;
      *(short8_t*)(f1h + off) = hv;
      *(short8_t*)(f1l + off) = lv;
    }
  }
  short8_t z = {0, 0, 0, 0, 0, 0, 0, 0};
  if (tid < 128) {            // col-64 pad for this quarter's rows
    int row = y0q + (tid >> 3), oct = tid & 7;
    size_t off = fbase + (size_t)row * 4160 + 64 * 64 + oct * 8;
    *(short8_t*)(f1h + off) = z;
    *(short8_t*)(f1l + off) = z;
  }
  if (qd == 3) {              // row-64 pad (all 65 cols)
    for (int i = tid; i < 520; i += 512) {
      int col = i >> 3, oct = i & 7;
      size_t off = fbase + (size_t)64 * 4160 + col * 64 + oct * 8;
      *(short8_t*)(f1h + off) = z;
      *(short8_t*)(f1l + off) = z;
    }
  }
}

// ---- conv2: f1 (split bf16) -> MFMA -> relu -> feat2 (256,64,32,32) fp32 ----
// grid 256 per batch: block = (nl, qd). wave: nt = w&3 (co group), mgg = qd*2 + (w>>2).
__global__ __launch_bounds__(512, 2) void conv2_kernel(const ushort_t* __restrict__ f1h,
                                                       const ushort_t* __restrict__ f1l,
                                                       const ushort_t* __restrict__ w2fh,
                                                       const ushort_t* __restrict__ w2fl,
                                                       const float* __restrict__ b2,
                                                       float* __restrict__ feat2, int n0) {
  int bx = blockIdx.x;
  int qd = bx & 3;
  int nl = bx >> 2;
  int n = n0 + nl;
  int tid = threadIdx.x;
  int wave = __builtin_amdgcn_readfirstlane(tid >> 6);
  int lane = tid & 63;
  int nt = wave & 3;
  int mgg = qd * 2 + (wave >> 2);
  int m = lane & 15, kg = lane >> 4;
  const ushort_t* fh = f1h + (size_t)nl * 270400;
  const ushort_t* fl = f1l + (size_t)nl * 270400;
  f32x4 acc[8] = {};
  for (int t9 = 0; t9 < 9; t9++) {
    int ky = (t9 >= 6) ? 2 : ((t9 >= 3) ? 1 : 0);
    int kx = t9 - ky * 3;
    #pragma unroll
    for (int q = 0; q < 2; q++) {
      int widx = (((t9 * 2 + q) * 4 + nt) * 64 + lane) * 8;
      short8_t Bh = *(const short8_t*)(w2fh + widx);
      short8_t Bl = *(const short8_t*)(w2fl + widx);
      #pragma unroll
      for (int i = 0; i < 8; i++) {
        int tile = mgg * 8 + i;
        int oy = tile >> 1, ox0 = (tile & 1) << 4;
        int off = (2 * oy + ky) * 4160 + (2 * (ox0 + m) + kx) * 64 + q * 32 + kg * 8;
        short8_t Ah = *(const short8_t*)(fh + off);
        short8_t Al = *(const short8_t*)(fl + off);
        acc[i] = __builtin_amdgcn_mfma_f32_16x16x32_bf16(Ah, Bh, acc[i], 0, 0, 0);
        acc[i] = __builtin_amdgcn_mfma_f32_16x16x32_bf16(Ah, Bl, acc[i], 0, 0, 0);
        acc[i] = __builtin_amdgcn_mfma_f32_16x16x32_bf16(Al, Bh, acc[i], 0, 0, 0);
      }
    }
  }
  int co = nt * 16 + m;
  float bv = b2[co];
  #pragma unroll
  for (int i = 0; i < 8; i++) {
    int tile = mgg * 8 + i;
    int oy = tile >> 1, ox0 = (tile & 1) << 4;
    float4 o;
    o.x = fmaxf(acc[i][0] + bv, 0.f);
    o.y = fmaxf(acc[i][1] + bv, 0.f);
    o.z = fmaxf(acc[i][2] + bv, 0.f);
    o.w = fmaxf(acc[i][3] + bv, 0.f);
    *(float4*)&feat2[(((size_t)n * 64 + co) * 32 + oy) * 32 + ox0 + kg * 4] = o;
  }
}

// ================= cooperative tail kernel =================
struct CoopArgs {
  const float *feat2, *rois, *src_coor, *rbuf;
  float *pool, *cat, *obj, *sbuf, *cs, *dout;
  const float *fc0T, *fc0_b, *fc0c_w, *fc0c_b, *fc1cT, *fc1c_b, *redT, *red_b;
  const float *aggT, *agg_b, *decw, *decb;
  const float *selfT, *uT, *vT, *affT, *outAT, *outST;
  const float *self_b, *rel_b, *aff_b, *out_b;
};

__device__ __forceinline__ void gemm_unit(const float* A, int lda, const float* WT,
                                          const float* bias, float* C, int ldc, int coff,
                                          int kshift, int r0, float* As, int tid) {
  __syncthreads();
  int K = 1 << kshift;
  for (int idx = tid; idx < 8 * K; idx += 512)
    As[idx] = A[(r0 + (idx >> kshift)) * lda + (idx & (K - 1))];
  __syncthreads();
  int d = tid & 255;
  int half = __builtin_amdgcn_readfirstlane(tid >> 8);
  float acc[4] = {};
  const float* asb = As + half * 4 * K;
  for (int kq = 0; kq < (K >> 2); kq++) {
    float4 wv = *(const float4*)(WT + kq * 1024 + d * 4);
    #pragma unroll
    for (int rr = 0; rr < 4; rr++) {
      float4 a4 = *(const float4*)(asb + rr * K + kq * 4);
      FMA4(acc[rr], a4, wv);
    }
  }
  float bv = bias[d];
  #pragma unroll
  for (int rr = 0; rr < 4; rr++)
    C[(r0 + half * 4 + rr) * ldc + coff + d] = fmaxf(acc[rr] + bv, 0.f);
}

__device__ __forceinline__ void emb_unit(int r0, float* As, int tid, const CoopArgs& a) {
  __syncthreads();
  for (int idx = tid; idx < 2048; idx += 512) {
    int rr = idx >> 8, c = idx & 255;
    const float* cp = a.src_coor + (size_t)(r0 + rr) * 2;
    float v = cp[0] * a.fc0c_w[c * 2] + cp[1] * a.fc0c_w[c * 2 + 1] + a.fc0c_b[c];
    As[idx] = fmaxf(v, 0.f);
  }
  __syncthreads();
  int d = tid & 255;
  int half = __builtin_amdgcn_readfirstlane(tid >> 8);
  float acc[4] = {};
  const float* asb = As + half * 4 * 256;
  for (int kq = 0; kq < 64; kq++) {
    float4 wv = *(const float4*)(a.fc1cT + kq * 1024 + d * 4);
    #pragma unroll
    for (int rr = 0; rr < 4; rr++) {
      float4 a4 = *(const float4*)(asb + rr * 256 + kq * 4);
      FMA4(acc[rr], a4, wv);
    }
  }
  float bv = a.fc1c_b[d];
  #pragma unroll
  for (int rr = 0; rr < 4; rr++)
    a.cat[(r0 + half * 4 + rr) * 512 + 256 + d] = fmaxf(acc[rr] + bv, 0.f);
}

__device__ __forceinline__ void internet_body(int j, int bx, int tid, float* sh,
                                              float* coor_lds, float* r_lds, float (*mw)[8],
                                              const CoopArgs& a) {
  float* s_lds = sh;
  float* v_lds = sh + 1536;
  float* h_lds = sh + 3072;
  float* a_lds = sh + 4608;
  int xcd = bx & 7;
  int k = __builtin_amdgcn_readfirstlane(xcd >> 1);
  int b = __builtin_amdgcn_readfirstlane(((xcd & 1) << 5) + (bx >> 3));
  int sl = j + k;
  const float* srow = (sl < 4) ? (a.obj + (b * 4 + sl) * 6 * 256)
                               : (a.sbuf + ((sl - 4) * 64 + b) * 6 * 256);
  for (int idx = tid; idx < 1536; idx += 512) s_lds[idx] = srow[idx];
  if (tid < 6) r_lds[tid] = a.rbuf[b * 6 + tid];
  bool dodec = (k == 3) && (j >= 1);
  if (!dodec && tid < 12) {
    int i = tid >> 1, c = tid & 1;
    coor_lds[tid] = (sl < 4) ? a.src_coor[((b * 4 + sl) * 6 + i) * 2 + c]
                             : a.dout[((b * 8 + (sl - 4)) * 6 + i) * 4 + 2 + c];
  }
  __syncthreads();
  if (dodec && tid < 384) {
    int lane16 = tid & 15;
    int p = tid >> 4;
    int i = p >> 2, o = p & 3;
    float a2 = 0.f;
    #pragma unroll
    for (int m = 0; m < 16; m++) {
      int dd = lane16 + m * 16;
      a2 = fmaf(s_lds[i * 256 + dd], a.decw[o * 256 + dd], a2);
    }
    a2 += __shfl_down(a2, 8, 16);
    a2 += __shfl_down(a2, 4, 16);
    a2 += __shfl_down(a2, 2, 16);
    a2 += __shfl_down(a2, 1, 16);
    if (lane16 == 0) {
      float val = a2 + a.decb[o];
      a.dout[((b * 8 + (j - 1)) * 6 + i) * 4 + o] = val;
      if (o >= 2) coor_lds[i * 2 + (o - 2)] = val;
    }
  }
  __syncthreads();
  if (tid < 36) {
    int i = tid / 6, jj = tid % 6;
    float dx = coor_lds[i * 2] - coor_lds[jj * 2];
    float dy = coor_lds[i * 2 + 1] - coor_lds[jj * 2 + 1];
    float dist = sqrtf(dx * dx + dy * dy);
    mw[i][jj] = (i != jj && dist <= r_lds[i] + r_lds[jj]) ? 1.f : 0.f;
  }
  int d = tid & 255;
  int half = __builtin_amdgcn_readfirstlane(tid >> 8);
  const float* sT = a.selfT + k * 65536;
  const float* uTk = a.uT + k * 65536;
  const float* vTk = a.vT + k * 65536;
  const float* sbase = s_lds + half * 3 * 256;
  float as[3] = {}, au[3] = {}, av[3] = {};
  for (int kq = 0; kq < 64; kq++) {
    float4 ws = *(const float4*)(sT + kq * 1024 + d * 4);
    float4 wu = *(const float4*)(uTk + kq * 1024 + d * 4);
    float4 wv = *(const float4*)(vTk + kq * 1024 + d * 4);
    #pragma unroll
    for (int rr = 0; rr < 3; rr++) {
      float4 a4 = *(const float4*)(sbase + rr * 256 + kq * 4);
      FMA4(as[rr], a4, ws);
      FMA4(au[rr], a4, wu);
      FMA4(av[rr], a4, wv);
    }
  }
  #pragma unroll
  for (int rr = 0; rr < 3; rr++) v_lds[(half * 3 + rr) * 256 + d] = av[rr];
  __syncthreads();
  float sbv = a.self_b[k * 256 + d];
  float rbv = a.rel_b[k * 256 + d];
  #pragma unroll
  for (int rr = 0; rr < 3; rr++) {
    int i = half * 3 + rr;
    float cnt = mw[i][0] + mw[i][1] + mw[i][2] + mw[i][3] + mw[i][4] + mw[i][5];
    float relsum = cnt * (au[rr] + rbv);
    #pragma unroll
    for (int jj = 0; jj < 6; jj++)
      relsum = fmaf(mw[i][jj], v_lds[jj * 256 + d], relsum);
    h_lds[i * 256 + d] = as[rr] + sbv + relsum;
  }
  __syncthreads();
  const float* aT = a.affT + k * 65536;
  const float* hbase = h_lds + half * 3 * 256;
  float aa[3] = {};
  for (int kq = 0; kq < 64; kq++) {
    float4 wv = *(const float4*)(aT + kq * 1024 + d * 4);
    #pragma unroll
    for (int rr = 0; rr < 3; rr++) {
      float4 a4 = *(const float4*)(hbase + rr * 256 + kq * 4);
      FMA4(aa[rr], a4, wv);
    }
  }
  float abv = a.aff_b[k * 256 + d];
  #pragma unroll
  for (int rr = 0; rr < 3; rr++)
    a_lds[(half * 3 + rr) * 256 + d] = fmaxf(aa[rr] + abv, 0.f);
  __syncthreads();
  const float* oaT = a.outAT + k * 65536;
  const float* osT = a.outST + k * 65536;
  const float* abase = a_lds + half * 3 * 256;
  float ao[3] = {};
  for (int kq = 0; kq < 64; kq++) {
    float4 wa = *(const float4*)(oaT + kq * 1024 + d * 4);
    float4 wsv = *(const float4*)(osT + kq * 1024 + d * 4);
    #pragma unroll
    for (int rr = 0; rr < 3; rr++) {
      float4 a4 = *(const float4*)(abase + rr * 256 + kq * 4);
      float4 s4 = *(const float4*)(sbase + rr * 256 + kq * 4);
      FMA4(ao[rr], a4, wa);
      FMA4(ao[rr], s4, wsv);
    }
  }
  float obv = a.out_b[k * 256 + d];
  #pragma unroll
  for (int rr = 0; rr < 3; rr++)
    a.cs[(b * 6 + half * 3 + rr) * 1024 + k * 256 + d] = fmaxf(ao[rr] + obv, 0.f);
}

__device__ __forceinline__ void agg_body(int j, int bx, int tid, float* sh, const CoopArgs& a) {
  float* cs_lds = sh;
  int dq = bx & 3;
  int b = bx >> 2;
  for (int idx = tid; idx < 6144; idx += 512) cs_lds[idx] = a.cs[b * 6144 + idx];
  __syncthreads();
  int d = tid & 63;
  int i = tid >> 6;
  if (i < 6) {
    float acc = 0.f;
    const float* wp = a.aggT + (dq * 64 + d) * 4;
    const float* ap = cs_lds + i * 1024;
    for (int kq = 0; kq < 256; kq++) {
      float4 wv = *(const float4*)(wp + kq * 1024);
      float4 a4 = *(const float4*)(ap + kq * 4);
      FMA4(acc, a4, wv);
    }
    a.sbuf[((j * 64 + b) * 6 + i) * 256 + dq * 64 + d] = acc + a.agg_b[dq * 64 + d];
  }
}

__global__ __launch_bounds__(512) void coop_kernel(CoopArgs a) {
  __shared__ __align__(16) float sh[8192];
  __shared__ float coor_lds[12], r_lds[6], mw[6][8];
  int bx = blockIdx.x;
  int tid = threadIdx.x;
  cg::grid_group g = cg::this_grid();

  // stage A: roi_align -> pool
  for (int o = bx * 512 + tid; o < RTOT * 1024; o += 131072) {
    int px = o & 3, py = (o >> 2) & 3, c = (o >> 4) & 63, r = o >> 10;
    const float* rp = a.rois + r * 5;
    int bi = (int)rp[0];
    float x1 = rp[1] * 0.25f, y1 = rp[2] * 0.25f, x2 = rp[3] * 0.25f, y2 = rp[4] * 0.25f;
    float bw = fmaxf(x2 - x1, 1.0f) * 0.25f;
    float bh = fmaxf(y2 - y1, 1.0f) * 0.25f;
    float sx = x1 + bw * (px + 0.5f);
    float sy = y1 + bh * (py + 0.5f);
    float x0f = fminf(fmaxf(floorf(sx), 0.f), 31.f);
    float y0f = fminf(fmaxf(floorf(sy), 0.f), 31.f);
    float lx = fminf(fmaxf(sx - x0f, 0.f), 1.f);
    float ly = fminf(fmaxf(sy - y0f, 0.f), 1.f);
    int ix0 = (int)x0f, iy0 = (int)y0f;
    int ix1 = min(ix0 + 1, 31), iy1 = min(iy0 + 1, 31);
    const float* f = a.feat2 + (bi * 64 + c) * 1024;
    float v00 = f[iy0 * 32 + ix0], v01 = f[iy0 * 32 + ix1];
    float v10 = f[iy1 * 32 + ix0], v11 = f[iy1 * 32 + ix1];
    a.pool[o] = v00 * (1 - ly) * (1 - lx) + v01 * (1 - ly) * lx + v10 * ly * (1 - lx) +
                v11 * ly * lx;
  }
  g.sync();
  // stage B: fc0 (units 0..191) + emb->fc1c (units 192..383)
  for (int u = bx; u < 384; u += 256) {
    if (u < 192) gemm_unit(a.pool, 1024, a.fc0T, a.fc0_b, a.cat, 512, 0, 10, u * 8, sh, tid);
    else emb_unit((u - 192) * 8, sh, tid, a);
  }
  g.sync();
  // stage C: red
  if (bx < 192) gemm_unit(a.cat, 512, a.redT, a.red_b, a.obj, 256, 0, 9, bx * 8, sh, tid);
  g.sync();
  // rollouts
  for (int j = 0; j < 8; j++) {
    internet_body(j, bx, tid, sh, coor_lds, r_lds, mw, a);
    g.sync();
    agg_body(j, bx, tid, sh, a);
    g.sync();
  }
  // final dec (rollout 7)
  if (bx < 64 && tid < 384) {
    int lane16 = tid & 15;
    int p = tid >> 4;
    int i = p >> 2, o = p & 3;
    const float* sp = a.sbuf + ((size_t)(7 * 64 + bx) * 6 + i) * 256;
    float a2 = 0.f;
    #pragma unroll
    for (int m = 0; m < 16; m++) {
      int dd = lane16 + m * 16;
      a2 = fmaf(sp[dd], a.decw[o * 256 + dd], a2);
    }
    a2 += __shfl_down(a2, 8, 16);
    a2 += __shfl_down(a2, 4, 16);
    a2 += __shfl_down(a2, 2, 16);
    a2 += __shfl_down(a2, 1, 16);
    if (lane16 == 0) a.dout[((bx * 8 + 7) * 6 + i) * 4 + o] = a2 + a.decb[o];
  }
}

extern "C" void kernel_launch(void* const* d_in, const int* in_sizes, int n_in,
                              void* d_out, int out_size, void* d_ws, size_t ws_size,
                              hipStream_t stream) {
  const float* x        = (const float*)d_in[0];
  const float* rois     = (const float*)d_in[1];
  const float* src_coor = (const float*)d_in[2];
  const float* w_conv1  = (const float*)d_in[3];
  const float* b_conv1  = (const float*)d_in[4];
  const float* w_conv2  = (const float*)d_in[5];
  const float* b_conv2  = (const float*)d_in[6];
  const float* fc0_w    = (const float*)d_in[7];
  const float* fc0_b    = (const float*)d_in[8];
  const float* fc0c_w   = (const float*)d_in[9];
  const float* fc0c_b   = (const float*)d_in[10];
  const float* fc1c_w   = (const float*)d_in[11];
  const float* fc1c_b   = (const float*)d_in[12];
  const float* red_w    = (const float*)d_in[13];
  const float* red_b    = (const float*)d_in[14];
  const float* g_self_w = (const float*)d_in[15];
  const float* g_self_b = (const float*)d_in[16];
  const float* g_rel_w  = (const float*)d_in[17];
  const float* g_rel_b  = (const float*)d_in[18];
  const float* g_aff_w  = (const float*)d_in[19];
  const float* g_aff_b  = (const float*)d_in[20];
  const float* g_out_w  = (const float*)d_in[21];
  const float* g_out_b  = (const float*)d_in[22];
  const float* agg_w    = (const float*)d_in[23];
  const float* agg_b    = (const float*)d_in[24];
  const float* dec_w    = (const float*)d_in[25];
  const float* dec_b    = (const float*)d_in[26];
  float* out = (float*)d_out;

  float* ws = (float*)d_ws;
  size_t off = 0;
  auto alloc = [&](size_t nf) { float* p = ws + off; off += (nf + 63) & ~(size_t)63; return p; };
  float* feat2 = alloc(16777216);   // (256,64,32,32)
  float* pool  = alloc(1572864);
  float* cat   = alloc(786432);
  float* obj   = alloc(393216);
  float* sbuf  = alloc(786432);
  float* cs    = alloc(393216);
  float* rbuf  = alloc(384);
  float* fc0T  = alloc(262144);
  float* fc1cT = alloc(65536);
  float* redT  = alloc(131072);
  float* aggT  = alloc(262144);
  float* selfT = alloc(262144);
  float* uT    = alloc(262144);
  float* vT    = alloc(262144);
  float* affT  = alloc(262144);
  float* outAT = alloc(262144);
  float* outST = alloc(262144);
  float* w1p   = alloc(1728);
  ushort_t* w2fh = (ushort_t*)alloc(18432);
  ushort_t* w2fl = (ushort_t*)alloc(18432);
  ushort_t* f1h  = (ushort_t*)alloc(8652800);   // 64 imgs × 270400 shorts
  ushort_t* f1l  = (ushort_t*)alloc(8652800);
  // total ≈ 40.3M floats ≈ 161 MB

  MatDescs md;
  int mi = 0;
  auto add = [&](const float* s, float* dstp, int ksh, int stride, int coff) {
    md.m[mi].src = s; md.m[mi].dst = dstp; md.m[mi].kshift = ksh;
    md.m[mi].stride = stride; md.m[mi].coff = coff; mi++;
  };
  add(fc0_w,  fc0T,  10, 1024, 0);
  add(fc1c_w, fc1cT, 8,  256,  0);
  add(red_w,  redT,  9,  512,  0);
  add(agg_w,  aggT,  10, 1024, 0);
  for (int k = 0; k < 4; k++) {
    add(g_self_w + k * 65536,  selfT + k * 65536, 8, 256, 0);
    add(g_rel_w  + k * 131072, uT    + k * 65536, 8, 512, 0);
    add(g_rel_w  + k * 131072, vT    + k * 65536, 8, 512, 256);
    add(g_aff_w  + k * 65536,  affT  + k * 65536, 8, 256, 0);
    add(g_out_w  + k * 131072, outAT + k * 65536, 8, 512, 0);
    add(g_out_w  + k * 131072, outST + k * 65536, 8, 512, 256);
  }

  prep_mats<<<dim3(1024, 28), dim3(256), 0, stream>>>(md);
  prep_small<<<dim3(154), dim3(256), 0, stream>>>(w_conv1, w_conv2, rois, w1p, w2fh, w2fl, rbuf);
  for (int b = 0; b < 4; b++) {
    conv1_kernel<<<dim3(256), dim3(512), 0, stream>>>(x, w1p, b_conv1, f1h, f1l, b * 64);
    conv2_kernel<<<dim3(256), dim3(512), 0, stream>>>(f1h, f1l, w2fh, w2fl, b_conv2, feat2, b * 64);
  }
  CoopArgs ca;
  ca.feat2 = feat2; ca.rois = rois; ca.src_coor = src_coor; ca.rbuf = rbuf;
  ca.pool = pool; ca.cat = cat; ca.obj = obj; ca.sbuf = sbuf; ca.cs = cs; ca.dout = out;
  ca.fc0T = fc0T; ca.fc0_b = fc0_b; ca.fc0c_w = fc0c_w; ca.fc0c_b = fc0c_b;
  ca.fc1cT = fc1cT; ca.fc1c_b = fc1c_b; ca.redT = redT; ca.red_b = red_b;
  ca.aggT = aggT; ca.agg_b = agg_b; ca.decw = dec_w; ca.decb = dec_b;
  ca.selfT = selfT; ca.uT = uT; ca.vT = vT; ca.affT = affT; ca.outAT = outAT; ca.outST = outST;
  ca.self_b = g_self_b; ca.rel_b = g_rel_b; ca.aff_b = g_aff_b; ca.out_b = g_out_b;
  void* kargs[] = { &ca };
  hipLaunchCooperativeKernel((const void*)coop_kernel, dim3(256), dim3(512), kargs, 0, stream);
  (void)in_sizes; (void)n_in; (void)out_size; (void)ws_size;
}

// Round 6
// 843.701 us; speedup vs baseline: 2.7980x; 2.7980x over previous
//
#include <hip/hip_runtime.h>

// Problem constants
#define BB 64
#define TT 4
#define NOBJ 6
#define RTOT 1536   // B*T*N
#define DD 256

typedef unsigned short ushort_t;
typedef __attribute__((ext_vector_type(8))) short short8_t;   // 8 bf16 (4 VGPRs)
typedef __attribute__((ext_vector_type(4))) float f32x4;

struct MatDesc { const float* src; float* dst; int kshift; int stride; int coff; };
struct MatDescs { MatDesc m[4]; };

#define FMA4(ACC, A4, W4) do { \
  ACC = fmaf((A4).x, (W4).x, ACC); \
  ACC = fmaf((A4).y, (W4).y, ACC); \
  ACC = fmaf((A4).z, (W4).z, ACC); \
  ACC = fmaf((A4).w, (W4).w, ACC); } while(0)

#define MFMA_BF16_16x16x32 __builtin_amdgcn_mfma_f32_16x16x32_bf16

__device__ __forceinline__ void split_bf16(float v, ushort_t& hs, ushort_t& ls) {
  unsigned int bits = __float_as_uint(v);
  hs = (ushort_t)(bits >> 16);
  float hf = __uint_as_float(bits & 0xFFFF0000u);
  ls = (ushort_t)(__float_as_uint(v - hf) >> 16);
}

// ---- prep: transpose weight mats into WT[kq][d][4] layout (fc0, fc1c, red, agg) ----
__global__ void prep_mats(MatDescs md) {
  const MatDesc de = md.m[blockIdx.y];
  int K = 1 << de.kshift;
  int idx = blockIdx.x * 256 + threadIdx.x;
  if (idx >= (256 << de.kshift)) return;
  int d = idx >> de.kshift;
  int kk = idx & (K - 1);
  de.dst[(kk >> 2) * 1024 + d * 4 + (kk & 3)] = de.src[d * de.stride + de.coff + kk];
}

// ---- prep: w1p[tap*64+co], conv2 split-bf16 planes, rbuf ----
__global__ void prep_small(const float* __restrict__ w1, const float* __restrict__ w2,
                           const float* __restrict__ rois, float* __restrict__ w1p,
                           ushort_t* __restrict__ w2fh, ushort_t* __restrict__ w2fl,
                           float* __restrict__ rbuf) {
  int idx = blockIdx.x * 256 + threadIdx.x;
  if (idx < 1728) w1p[idx] = w1[(idx & 63) * 27 + (idx >> 6)];
  int i2 = idx - 2048;
  if (i2 >= 0 && i2 < 36864) {
    int j = i2 & 7, lane = (i2 >> 3) & 63, nt = (i2 >> 9) & 3, q = (i2 >> 11) & 1, t = i2 >> 12;
    int co = nt * 16 + (lane & 15);
    int ci = q * 32 + ((lane >> 4) << 3) + j;
    ushort_t hs, ls;
    split_bf16(w2[(co * 64 + ci) * 9 + t], hs, ls);
    w2fh[i2] = hs; w2fl[i2] = ls;
  }
  int i3 = idx - 38912;
  if (i3 >= 0 && i3 < 384) {
    int b = i3 / 6, n = i3 % 6;
    float acc = 0.f;
    for (int t = 0; t < TT; t++) {
      const float* rp = rois + ((b * TT + t) * NOBJ + n) * 5;
      acc += (rp[4] - rp[2]) * 0.5f + (rp[3] - rp[1]) * 0.5f;
    }
    rbuf[i3] = acc * 0.125f;
  }
}

// ---- prep rollout B-fragments (bf16 hi/lo) ----
// B1 per k:  [nt48][kq8][lane][8j]  (nt<16: self, 16..31: u=rel[:, :256], 32..47: v=rel[:,256:])
// Baff per k: [nt16][kq8][lane][8j]
// Bout per k: [nt16][kq16][lane][8j] (kin 0..511 over [a|s])
__global__ void prep_rollB(const float* __restrict__ g_self_w, const float* __restrict__ g_rel_w,
                           const float* __restrict__ g_aff_w, const float* __restrict__ g_out_w,
                           ushort_t* __restrict__ b1h, ushort_t* __restrict__ b1l,
                           ushort_t* __restrict__ bafh, ushort_t* __restrict__ bafl,
                           ushort_t* __restrict__ bouh, ushort_t* __restrict__ boul) {
  int idx = blockIdx.x * 256 + threadIdx.x;
  if (idx >= 1572864) return;
  int k = idx / 393216;
  int r = idx - k * 393216;
  ushort_t hs, ls;
  if (r < 196608) {
    int j = r & 7, lane = (r >> 3) & 63, kq = (r >> 9) & 7, nt = r >> 12;
    int kin = kq * 32 + ((lane >> 4) << 3) + j;
    int d = (nt & 15) * 16 + (lane & 15);
    int mat = nt >> 4;
    float v = (mat == 0) ? g_self_w[(k * 256 + d) * 256 + kin]
                         : g_rel_w[(k * 256 + d) * 512 + (mat == 2 ? 256 : 0) + kin];
    split_bf16(v, hs, ls);
    b1h[k * 196608 + r] = hs; b1l[k * 196608 + r] = ls;
  } else if (r < 262144) {
    int r2 = r - 196608;
    int j = r2 & 7, lane = (r2 >> 3) & 63, kq = (r2 >> 9) & 7, nt = r2 >> 12;
    int kin = kq * 32 + ((lane >> 4) << 3) + j;
    int d = nt * 16 + (lane & 15);
    split_bf16(g_aff_w[(k * 256 + d) * 256 + kin], hs, ls);
    bafh[k * 65536 + r2] = hs; bafl[k * 65536 + r2] = ls;
  } else {
    int r3 = r - 262144;
    int j = r3 & 7, lane = (r3 >> 3) & 63, kq = (r3 >> 9) & 15, nt = r3 >> 13;
    int kin = kq * 32 + ((lane >> 4) << 3) + j;
    int d = nt * 16 + (lane & 15);
    split_bf16(g_out_w[(k * 256 + d) * 512 + kin], hs, ls);
    bouh[k * 131072 + r3] = hs; boul[k * 131072 + r3] = ls;
  }
}

// ---- fused conv1(fp32 vector) + conv2(split-bf16 MFMA) — round-4 verbatim ----
__global__ __launch_bounds__(512, 4) void convmf_kernel(const float* __restrict__ x,
                                                        const float* __restrict__ w1p,
                                                        const float* __restrict__ b1,
                                                        const ushort_t* __restrict__ w2fh,
                                                        const ushort_t* __restrict__ w2fl,
                                                        const float* __restrict__ b2,
                                                        float* __restrict__ feat2) {
  __shared__ __align__(16) float xs[3 * 11 * 72];
  __shared__ __align__(16) ushort_t f1h[5 * 34 * 72];
  __shared__ __align__(16) ushort_t f1l[5 * 34 * 72];
  int bx = blockIdx.x;
  int h = bx & 1;
  int band = (bx >> 1) & 15;
  int n = bx >> 5;
  int tid = threadIdx.x;
  int wave = __builtin_amdgcn_readfirstlane(tid >> 6);
  int lane = tid & 63;
  for (int i = tid; i < 3 * 11 * 72; i += 512) {
    int c = i % 72;
    int row = (i / 72) % 11;
    int ci = i / (72 * 11);
    int gr = 8 * band + row;
    int gc = h * 64 + c;
    float v = 0.f;
    if (gr < 128 && gc < 128 && c < 68) v = x[((n * 3 + ci) * 128 + gr) * 128 + gc];
    xs[(ci * 11 + row) * 72 + c] = v;
  }
  __syncthreads();
  int chb = wave * 8;
  int r0 = lane >> 4;
  int cp0 = lane & 15;
  int rB, xB;
  if (lane < 16) { rB = 4; xB = 4 * cp0; }
  else { int rr = lane - 16; rB = (rr < 5) ? rr : 0; xB = 64; }
  float a0[2][8] = {}; float aB[2][8] = {};
  for (int ci = 0; ci < 3; ci++) {
    #pragma unroll
    for (int ky = 0; ky < 3; ky++) {
      const float* wp = w1p + ((ci * 3 + ky) * 3) * 64 + chb;
      float wv[3][8];
      #pragma unroll
      for (int kx = 0; kx < 3; kx++)
        #pragma unroll
        for (int j = 0; j < 8; j++) wv[kx][j] = wp[kx * 64 + j];
      const float* x0 = &xs[(ci * 11 + 2 * r0 + ky) * 72 + 4 * cp0];
      float4 e4 = *(const float4*)x0; float e5 = x0[4];
      float xv[5] = {e4.x, e4.y, e4.z, e4.w, e5};
      #pragma unroll
      for (int c = 0; c < 2; c++)
        #pragma unroll
        for (int kx = 0; kx < 3; kx++) {
          float xx = xv[2 * c + kx];
          #pragma unroll
          for (int j = 0; j < 8; j++) a0[c][j] = fmaf(xx, wv[kx][j], a0[c][j]);
        }
      const float* x1 = &xs[(ci * 11 + 2 * rB + ky) * 72 + xB];
      float4 f4 = *(const float4*)x1; float f5 = x1[4];
      float yv[5] = {f4.x, f4.y, f4.z, f4.w, f5};
      #pragma unroll
      for (int c = 0; c < 2; c++)
        #pragma unroll
        for (int kx = 0; kx < 3; kx++) {
          float xx = yv[2 * c + kx];
          #pragma unroll
          for (int j = 0; j < 8; j++) aB[c][j] = fmaf(xx, wv[kx][j], aB[c][j]);
        }
    }
  }
  float bb[8];
  #pragma unroll
  for (int j = 0; j < 8; j++) bb[j] = b1[chb + j];
  int f1base = (8 * band) >> 1;   // = 4*band (first f1 row)
  auto storecol = [&](int row, int col, const float* a, bool ok) {
    short8_t hv, lv;
    #pragma unroll
    for (int j = 0; j < 8; j++) {
      float v = ok ? fmaxf(a[j] + bb[j], 0.f) : 0.f;
      unsigned int bits = __float_as_uint(v);
      hv[j] = (short)(bits >> 16);
      float hf = __uint_as_float(bits & 0xFFFF0000u);
      lv[j] = (short)(__float_as_uint(v - hf) >> 16);
    }
    int base = (row * 34 + col) * 72 + chb;
    *(short8_t*)&f1h[base] = hv;
    *(short8_t*)&f1l[base] = lv;
  };
  storecol(r0, 2 * cp0,     a0[0], true);
  storecol(r0, 2 * cp0 + 1, a0[1], true);
  if (lane < 16) {
    bool ok4 = (f1base + 4) < 64;
    storecol(4, 2 * cp0,     aB[0], ok4);
    storecol(4, 2 * cp0 + 1, aB[1], ok4);
  } else if (lane < 21) {
    int rr = lane - 16;
    bool okc = (h == 0) && ((f1base + rr) < 64);
    storecol(rr, 32, aB[0], okc);
  }
  __syncthreads();
  int nt = wave & 3, mg = wave >> 2;
  f32x4 acc = {0.f, 0.f, 0.f, 0.f};
  #pragma unroll
  for (int t = 0; t < 9; t++) {
    int ky = t / 3, kx = t % 3;
    int col = 2 * (lane & 15) + kx;
    int row = 2 * mg + ky;
    int abase = (row * 34 + col) * 72 + ((lane >> 4) << 3);
    #pragma unroll
    for (int q = 0; q < 2; q++) {
      int widx = (((t * 2 + q) * 4 + nt) * 64 + lane) * 8;
      short8_t Bh = *(const short8_t*)(w2fh + widx);
      short8_t Bl = *(const short8_t*)(w2fl + widx);
      short8_t Ah = *(const short8_t*)&f1h[abase + q * 32];
      short8_t Al = *(const short8_t*)&f1l[abase + q * 32];
      acc = MFMA_BF16_16x16x32(Ah, Bh, acc, 0, 0, 0);
      acc = MFMA_BF16_16x16x32(Ah, Bl, acc, 0, 0, 0);
      acc = MFMA_BF16_16x16x32(Al, Bh, acc, 0, 0, 0);
    }
  }
  int co = nt * 16 + (lane & 15);
  int oy = band * 2 + mg;
  int ox = h * 16 + ((lane >> 4) << 2);
  float bv = b2[co];
  float4 o;
  o.x = fmaxf(acc[0] + bv, 0.f);
  o.y = fmaxf(acc[1] + bv, 0.f);
  o.z = fmaxf(acc[2] + bv, 0.f);
  o.w = fmaxf(acc[3] + bv, 0.f);
  *(float4*)&feat2[((n * 64 + co) * 32 + oy) * 32 + ox] = o;
}

// ---- ROI align ----
__global__ void roi_pool_kernel(const float* __restrict__ feat2, const float* __restrict__ rois,
                                float* __restrict__ pool) {
  int o = blockIdx.x * 256 + threadIdx.x;
  if (o >= RTOT * 1024) return;
  int px = o & 3, py = (o >> 2) & 3, c = (o >> 4) & 63, r = o >> 10;
  const float* rp = rois + r * 5;
  int bi = (int)rp[0];
  float x1 = rp[1] * 0.25f, y1 = rp[2] * 0.25f, x2 = rp[3] * 0.25f, y2 = rp[4] * 0.25f;
  float bw = fmaxf(x2 - x1, 1.0f) * 0.25f;
  float bh = fmaxf(y2 - y1, 1.0f) * 0.25f;
  float sx = x1 + bw * (px + 0.5f);
  float sy = y1 + bh * (py + 0.5f);
  float x0f = fminf(fmaxf(floorf(sx), 0.f), 31.f);
  float y0f = fminf(fmaxf(floorf(sy), 0.f), 31.f);
  float lx = fminf(fmaxf(sx - x0f, 0.f), 1.f);
  float ly = fminf(fmaxf(sy - y0f, 0.f), 1.f);
  int ix0 = (int)x0f, iy0 = (int)y0f;
  int ix1 = min(ix0 + 1, 31), iy1 = min(iy0 + 1, 31);
  const float* f = feat2 + (bi * 64 + c) * 1024;
  float v00 = f[iy0 * 32 + ix0], v01 = f[iy0 * 32 + ix1];
  float v10 = f[iy1 * 32 + ix0], v11 = f[iy1 * 32 + ix1];
  pool[o] = v00 * (1 - ly) * (1 - lx) + v01 * (1 - ly) * lx + v10 * ly * (1 - lx) + v11 * ly * lx;
}

// ---- generic broadcast-row GEMM + bias + relu ----
__global__ __launch_bounds__(512) void gemmB_kernel(const float* __restrict__ A, int lda,
                                                    const float* __restrict__ WT,
                                                    const float* __restrict__ bias,
                                                    float* __restrict__ C, int ldc, int coff,
                                                    int kshift) {
  __shared__ __align__(16) float As[8 * 1024];
  int K = 1 << kshift;
  int tid = threadIdx.x;
  int r0 = blockIdx.x * 8;
  for (int idx = tid; idx < 8 * K; idx += 512)
    As[idx] = A[(r0 + (idx >> kshift)) * lda + (idx & (K - 1))];
  __syncthreads();
  int d = tid & 255;
  int half = __builtin_amdgcn_readfirstlane(tid >> 8);
  float acc[4] = {};
  const float* asb = As + half * 4 * K;
  for (int kq = 0; kq < (K >> 2); kq++) {
    float4 wv = *(const float4*)(WT + kq * 1024 + d * 4);
    #pragma unroll
    for (int rr = 0; rr < 4; rr++) {
      float4 a4 = *(const float4*)(asb + rr * K + kq * 4);
      FMA4(acc[rr], a4, wv);
    }
  }
  float bv = bias[d];
  #pragma unroll
  for (int rr = 0; rr < 4; rr++)
    C[(r0 + half * 4 + rr) * ldc + coff + d] = fmaxf(acc[rr] + bv, 0.f);
}

// ---- fused emb(2->256 relu) + fc1c(256->256 relu) -> cat[:,256:] ----
__global__ __launch_bounds__(512) void embgemm_kernel(const float* __restrict__ src_coor,
                                                      const float* __restrict__ w0,
                                                      const float* __restrict__ b0,
                                                      const float* __restrict__ fc1cT,
                                                      const float* __restrict__ b1,
                                                      float* __restrict__ cat) {
  __shared__ __align__(16) float As[8 * 256];
  int tid = threadIdx.x;
  int r0 = blockIdx.x * 8;
  for (int idx = tid; idx < 2048; idx += 512) {
    int rr = idx >> 8, c = idx & 255;
    const float* cp = src_coor + (size_t)(r0 + rr) * 2;
    float v = cp[0] * w0[c * 2] + cp[1] * w0[c * 2 + 1] + b0[c];
    As[idx] = fmaxf(v, 0.f);
  }
  __syncthreads();
  int d = tid & 255;
  int half = __builtin_amdgcn_readfirstlane(tid >> 8);
  float acc[4] = {};
  const float* asb = As + half * 4 * 256;
  for (int kq = 0; kq < 64; kq++) {
    float4 wv = *(const float4*)(fc1cT + kq * 1024 + d * 4);
    #pragma unroll
    for (int rr = 0; rr < 4; rr++) {
      float4 a4 = *(const float4*)(asb + rr * 256 + kq * 4);
      FMA4(acc[rr], a4, wv);
    }
  }
  float bv = b1[d];
  #pragma unroll
  for (int rr = 0; rr < 4; rr++)
    cat[(r0 + half * 4 + rr) * 512 + 256 + d] = fmaxf(acc[rr] + bv, 0.f);
}

// ---- internet via MFMA: 128 blocks = (k-XCD-pair, b-pair). M-dim packs 2 batches (12 rows). ----
__global__ __launch_bounds__(512) void internet_mfma(
    int j, const float* __restrict__ obj, const float* __restrict__ sbuf,
    const float* __restrict__ src_coor, float* __restrict__ dout,
    const float* __restrict__ rbuf, float* __restrict__ cs,
    const ushort_t* __restrict__ b1h, const ushort_t* __restrict__ b1l,
    const ushort_t* __restrict__ bafh, const ushort_t* __restrict__ bafl,
    const ushort_t* __restrict__ bouh, const ushort_t* __restrict__ boul,
    const float* __restrict__ self_b, const float* __restrict__ rel_b,
    const float* __restrict__ aff_b, const float* __restrict__ out_b,
    const float* __restrict__ decw, const float* __restrict__ decb) {
  // smem layout (bytes):
  //   [0,37440): asb/aub/avb fp32, stride 260 floats/row, 12 rows each (1040B*12=12480 each)
  //   [37440): sAh, [43776): sAl, [50112): hAh, [56448): hAl   (each 12*264 shorts=6336B)
  //   aAh aliases [0,6336), aAl [6336,12672)  (asb region, dead by then)
  __shared__ __align__(16) char smem[62784];
  __shared__ float coor_lds[2][12], r_lds[2][6], mw[2][6][8];
  float* bufA = (float*)smem;                       // asb = bufA, aub = bufA+3120, avb = bufA+6240
  ushort_t* sAh = (ushort_t*)(smem + 37440);
  ushort_t* sAl = (ushort_t*)(smem + 43776);
  ushort_t* hAh = (ushort_t*)(smem + 50112);
  ushort_t* hAl = (ushort_t*)(smem + 56448);
  ushort_t* aAh = (ushort_t*)(smem);
  ushort_t* aAl = (ushort_t*)(smem + 6336);

  int bx = blockIdx.x;
  int k = __builtin_amdgcn_readfirstlane((bx & 7) >> 1);
  int pb = __builtin_amdgcn_readfirstlane(((bx & 1) << 4) | (bx >> 3));   // 0..31
  int tid = threadIdx.x;
  int wave = __builtin_amdgcn_readfirstlane(tid >> 6);
  int lane = tid & 63;
  int m15 = lane & 15, quad = lane >> 4;
  int mrow = (m15 < 12) ? m15 : 0;
  int sl = j + k;
  const float* srow[2];
  #pragma unroll
  for (int bq = 0; bq < 2; bq++) {
    int b = pb * 2 + bq;
    srow[bq] = (sl < 4) ? (obj + (b * 4 + sl) * 1536) : (sbuf + ((sl - 4) * 64 + b) * 1536);
  }
  bool dodec = (k == 3) && (j >= 1);

  // P0: coor / dec / r / sA repack
  if (tid < 12) r_lds[tid / 6][tid % 6] = rbuf[(pb * 2 + tid / 6) * 6 + tid % 6];
  if (!dodec && tid < 24) {
    int bq = tid / 12, t12 = tid % 12;
    int i = t12 >> 1, c = t12 & 1;
    int b = pb * 2 + bq;
    coor_lds[bq][t12] = (sl < 4) ? src_coor[((b * 4 + sl) * 6 + i) * 2 + c]
                                 : dout[((b * 8 + (sl - 4)) * 6 + i) * 4 + 2 + c];
  }
  if (dodec && tid < 384) {
    int lane8 = tid & 7;
    int p = tid >> 3;            // 0..47
    int bq = p / 24, pp = p % 24;
    int i = pp >> 2, o = pp & 3;
    float a2 = 0.f;
    #pragma unroll
    for (int m = 0; m < 32; m++) {
      int dd = lane8 + m * 8;
      a2 = fmaf(srow[bq][i * 256 + dd], decw[o * 256 + dd], a2);
    }
    a2 += __shfl_down(a2, 4, 8);
    a2 += __shfl_down(a2, 2, 8);
    a2 += __shfl_down(a2, 1, 8);
    if (lane8 == 0) {
      float val = a2 + decb[o];
      int b = pb * 2 + bq;
      dout[((b * 8 + (j - 1)) * 6 + i) * 4 + o] = val;
      if (o >= 2) coor_lds[bq][i * 2 + (o - 2)] = val;
    }
  }
  for (int pos = tid; pos < 3072; pos += 512) {
    int row = pos >> 8, d = pos & 255;
    int bq = row >= 6, i = row - bq * 6;
    ushort_t hs, ls;
    split_bf16(srow[bq][i * 256 + d], hs, ls);
    sAh[row * 264 + d] = hs;
    sAl[row * 264 + d] = ls;
  }
  __syncthreads();

  // P1: mask + stage-1 MFMA (self|u|v as one N=768 GEMM)
  if (tid < 72) {
    int bq = tid / 36, rest = tid % 36;
    int i = rest / 6, jj = rest % 6;
    float dx = coor_lds[bq][i * 2] - coor_lds[bq][jj * 2];
    float dy = coor_lds[bq][i * 2 + 1] - coor_lds[bq][jj * 2 + 1];
    float dist = sqrtf(dx * dx + dy * dy);
    mw[bq][i][jj] = (i != jj && dist <= r_lds[bq][i] + r_lds[bq][jj]) ? 1.f : 0.f;
  }
  {
    f32x4 acc1[6] = {};
    const ushort_t* b1hk = b1h + (size_t)k * 196608;
    const ushort_t* b1lk = b1l + (size_t)k * 196608;
    for (int kq = 0; kq < 8; kq++) {
      int aoff = mrow * 264 + kq * 32 + quad * 8;
      short8_t Ah = *(const short8_t*)(sAh + aoff);
      short8_t Al = *(const short8_t*)(sAl + aoff);
      #pragma unroll
      for (int tt = 0; tt < 6; tt++) {
        int t = wave * 6 + tt;
        int bi = ((t * 8 + kq) * 64 + lane) * 8;
        short8_t Bh = *(const short8_t*)(b1hk + bi);
        short8_t Bl = *(const short8_t*)(b1lk + bi);
        acc1[tt] = MFMA_BF16_16x16x32(Ah, Bh, acc1[tt], 0, 0, 0);
        acc1[tt] = MFMA_BF16_16x16x32(Ah, Bl, acc1[tt], 0, 0, 0);
        acc1[tt] = MFMA_BF16_16x16x32(Al, Bh, acc1[tt], 0, 0, 0);
      }
    }
    #pragma unroll
    for (int tt = 0; tt < 6; tt++) {
      int t = wave * 6 + tt;
      int mat = t >> 4, ntm = t & 15;
      float* buf = bufA + mat * 3120;
      #pragma unroll
      for (int reg = 0; reg < 4; reg++) {
        int m = quad * 4 + reg;
        if (m < 12) buf[m * 260 + ntm * 16 + m15] = acc1[tt][reg];
      }
    }
  }
  __syncthreads();

  // P2: h = as + self_b + cnt*(au+rel_b) + sum_j mw*av ; repack -> hA
  for (int rr = 0; rr < 6; rr++) {
    int pos = rr * 512 + tid;
    int row = pos >> 8, d = pos & 255;
    int bq = row >= 6, i = row - bq * 6;
    float as = bufA[row * 260 + d];
    float au = bufA[3120 + row * 260 + d];
    float cnt = mw[bq][i][0] + mw[bq][i][1] + mw[bq][i][2] + mw[bq][i][3] + mw[bq][i][4] +
                mw[bq][i][5];
    float hsum = as + self_b[k * 256 + d] + cnt * (au + rel_b[k * 256 + d]);
    #pragma unroll
    for (int jj = 0; jj < 6; jj++)
      hsum = fmaf(mw[bq][i][jj], bufA[6240 + (bq * 6 + jj) * 260 + d], hsum);
    ushort_t hs, ls;
    split_bf16(hsum, hs, ls);
    hAh[row * 264 + d] = hs;
    hAl[row * 264 + d] = ls;
  }
  __syncthreads();

  // P3: aff MFMA -> relu -> aA (bf16 hi/lo, aliased over asb/aub region)
  {
    f32x4 acc2[2] = {};
    const ushort_t* bhk = bafh + (size_t)k * 65536;
    const ushort_t* blk = bafl + (size_t)k * 65536;
    for (int kq = 0; kq < 8; kq++) {
      int aoff = mrow * 264 + kq * 32 + quad * 8;
      short8_t Ah = *(const short8_t*)(hAh + aoff);
      short8_t Al = *(const short8_t*)(hAl + aoff);
      #pragma unroll
      for (int tt = 0; tt < 2; tt++) {
        int t = wave * 2 + tt;
        int bi = ((t * 8 + kq) * 64 + lane) * 8;
        short8_t Bh = *(const short8_t*)(bhk + bi);
        short8_t Bl = *(const short8_t*)(blk + bi);
        acc2[tt] = MFMA_BF16_16x16x32(Ah, Bh, acc2[tt], 0, 0, 0);
        acc2[tt] = MFMA_BF16_16x16x32(Ah, Bl, acc2[tt], 0, 0, 0);
        acc2[tt] = MFMA_BF16_16x16x32(Al, Bh, acc2[tt], 0, 0, 0);
      }
    }
    __syncthreads();   // asb/aub/avb fully read in P2; safe to overwrite with aA
    #pragma unroll
    for (int tt = 0; tt < 2; tt++) {
      int t = wave * 2 + tt;
      int d = t * 16 + m15;
      float bias = aff_b[k * 256 + d];
      #pragma unroll
      for (int reg = 0; reg < 4; reg++) {
        int m = quad * 4 + reg;
        if (m < 12) {
          float v = fmaxf(acc2[tt][reg] + bias, 0.f);
          ushort_t hs, ls;
          split_bf16(v, hs, ls);
          aAh[m * 264 + d] = hs;
          aAl[m * 264 + d] = ls;
        }
      }
    }
  }
  __syncthreads();

  // P4: out MFMA over K=512 ([a|s]) -> relu -> cs
  {
    f32x4 acc3[2] = {};
    const ushort_t* bhk = bouh + (size_t)k * 131072;
    const ushort_t* blk = boul + (size_t)k * 131072;
    for (int kq = 0; kq < 16; kq++) {
      const ushort_t* Abh = (kq < 8) ? (aAh + mrow * 264 + kq * 32)
                                     : (sAh + mrow * 264 + (kq - 8) * 32);
      const ushort_t* Abl = (kq < 8) ? (aAl + mrow * 264 + kq * 32)
                                     : (sAl + mrow * 264 + (kq - 8) * 32);
      short8_t Ah = *(const short8_t*)(Abh + quad * 8);
      short8_t Al = *(const short8_t*)(Abl + quad * 8);
      #pragma unroll
      for (int tt = 0; tt < 2; tt++) {
        int t = wave * 2 + tt;
        int bi = ((t * 16 + kq) * 64 + lane) * 8;
        short8_t Bh = *(const short8_t*)(bhk + bi);
        short8_t Bl = *(const short8_t*)(blk + bi);
        acc3[tt] = MFMA_BF16_16x16x32(Ah, Bh, acc3[tt], 0, 0, 0);
        acc3[tt] = MFMA_BF16_16x16x32(Ah, Bl, acc3[tt], 0, 0, 0);
        acc3[tt] = MFMA_BF16_16x16x32(Al, Bh, acc3[tt], 0, 0, 0);
      }
    }
    #pragma unroll
    for (int tt = 0; tt < 2; tt++) {
      int t = wave * 2 + tt;
      int d = t * 16 + m15;
      float bias = out_b[k * 256 + d];
      #pragma unroll
      for (int reg = 0; reg < 4; reg++) {
        int m = quad * 4 + reg;
        if (m < 12) {
          int bq = m >= 6, i = m - bq * 6;
          int b = pb * 2 + bq;
          cs[(b * 6 + i) * 1024 + k * 256 + d] = fmaxf(acc3[tt][reg] + bias, 0.f);
        }
      }
    }
  }
}

// ---- agg (d-sliced 4-wide) ----
__global__ __launch_bounds__(512) void agg4_kernel(int j, const float* __restrict__ cs,
                                                   const float* __restrict__ aggT,
                                                   const float* __restrict__ agg_b,
                                                   float* __restrict__ sbuf) {
  __shared__ __align__(16) float cs_lds[6 * 1024];
  int bx = blockIdx.x;
  int dq = bx & 3;
  int b = bx >> 2;
  int tid = threadIdx.x;
  for (int idx = tid; idx < 6144; idx += 512) cs_lds[idx] = cs[b * 6144 + idx];
  __syncthreads();
  int d = tid & 63;
  int i = tid >> 6;
  if (i < 6) {
    float acc = 0.f;
    const float* wp = aggT + (dq * 64 + d) * 4;
    const float* ap = cs_lds + i * 1024;
    for (int kq = 0; kq < 256; kq++) {
      float4 wv = *(const float4*)(wp + kq * 1024);
      float4 a4 = *(const float4*)(ap + kq * 4);
      FMA4(acc, a4, wv);
    }
    sbuf[((j * 64 + b) * 6 + i) * 256 + dq * 64 + d] = acc + agg_b[dq * 64 + d];
  }
}

// ---- final dec for rollout 7 ----
__global__ void dec_last(const float* __restrict__ sbuf, const float* __restrict__ decw,
                         const float* __restrict__ decb, float* __restrict__ dout) {
  int b = blockIdx.x;
  int tid = threadIdx.x;   // 384
  int lane16 = tid & 15;
  int p = tid >> 4;
  int i = p >> 2, o = p & 3;
  const float* sp = sbuf + ((size_t)(7 * 64 + b) * 6 + i) * 256;
  float a2 = 0.f;
  #pragma unroll
  for (int m = 0; m < 16; m++) {
    int dd = lane16 + m * 16;
    a2 = fmaf(sp[dd], decw[o * 256 + dd], a2);
  }
  a2 += __shfl_down(a2, 8, 16);
  a2 += __shfl_down(a2, 4, 16);
  a2 += __shfl_down(a2, 2, 16);
  a2 += __shfl_down(a2, 1, 16);
  if (lane16 == 0) dout[((b * 8 + 7) * 6 + i) * 4 + o] = a2 + decb[o];
}

extern "C" void kernel_launch(void* const* d_in, const int* in_sizes, int n_in,
                              void* d_out, int out_size, void* d_ws, size_t ws_size,
                              hipStream_t stream) {
  const float* x        = (const float*)d_in[0];
  const float* rois     = (const float*)d_in[1];
  const float* src_coor = (const float*)d_in[2];
  const float* w_conv1  = (const float*)d_in[3];
  const float* b_conv1  = (const float*)d_in[4];
  const float* w_conv2  = (const float*)d_in[5];
  const float* b_conv2  = (const float*)d_in[6];
  const float* fc0_w    = (const float*)d_in[7];
  const float* fc0_b    = (const float*)d_in[8];
  const float* fc0c_w   = (const float*)d_in[9];
  const float* fc0c_b   = (const float*)d_in[10];
  const float* fc1c_w   = (const float*)d_in[11];
  const float* fc1c_b   = (const float*)d_in[12];
  const float* red_w    = (const float*)d_in[13];
  const float* red_b    = (const float*)d_in[14];
  const float* g_self_w = (const float*)d_in[15];
  const float* g_self_b = (const float*)d_in[16];
  const float* g_rel_w  = (const float*)d_in[17];
  const float* g_rel_b  = (const float*)d_in[18];
  const float* g_aff_w  = (const float*)d_in[19];
  const float* g_aff_b  = (const float*)d_in[20];
  const float* g_out_w  = (const float*)d_in[21];
  const float* g_out_b  = (const float*)d_in[22];
  const float* agg_w    = (const float*)d_in[23];
  const float* agg_b    = (const float*)d_in[24];
  const float* dec_w    = (const float*)d_in[25];
  const float* dec_b    = (const float*)d_in[26];
  float* out = (float*)d_out;

  float* ws = (float*)d_ws;
  size_t off = 0;
  auto alloc = [&](size_t nf) { float* p = ws + off; off += (nf + 63) & ~(size_t)63; return p; };
  float* feat2 = alloc(16777216);   // (256,64,32,32)
  float* pool  = alloc(1572864);
  float* cat   = alloc(786432);
  float* obj   = alloc(393216);
  float* sbuf  = alloc(786432);
  float* cs    = alloc(393216);
  float* rbuf  = alloc(384);
  float* fc0T  = alloc(262144);
  float* fc1cT = alloc(65536);
  float* redT  = alloc(131072);
  float* aggT  = alloc(262144);
  float* w1p   = alloc(1728);
  ushort_t* w2fh = (ushort_t*)alloc(18432);
  ushort_t* w2fl = (ushort_t*)alloc(18432);
  ushort_t* b1h  = (ushort_t*)alloc(393216);   // 4k × 196608 shorts
  ushort_t* b1l  = (ushort_t*)alloc(393216);
  ushort_t* bafh = (ushort_t*)alloc(131072);   // 4k × 65536 shorts
  ushort_t* bafl = (ushort_t*)alloc(131072);
  ushort_t* bouh = (ushort_t*)alloc(262144);   // 4k × 131072 shorts
  ushort_t* boul = (ushort_t*)alloc(262144);
  // total ≈ 22.6M floats ≈ 90 MB

  MatDescs md;
  md.m[0] = {fc0_w,  fc0T,  10, 1024, 0};
  md.m[1] = {fc1c_w, fc1cT, 8,  256,  0};
  md.m[2] = {red_w,  redT,  9,  512,  0};
  md.m[3] = {agg_w,  aggT,  10, 1024, 0};

  prep_mats<<<dim3(1024, 4), dim3(256), 0, stream>>>(md);
  prep_small<<<dim3(154), dim3(256), 0, stream>>>(w_conv1, w_conv2, rois, w1p, w2fh, w2fl, rbuf);
  prep_rollB<<<dim3(6144), dim3(256), 0, stream>>>(g_self_w, g_rel_w, g_aff_w, g_out_w,
                                                   b1h, b1l, bafh, bafl, bouh, boul);
  convmf_kernel<<<dim3(8192), dim3(512), 0, stream>>>(x, w1p, b_conv1, w2fh, w2fl, b_conv2, feat2);
  roi_pool_kernel<<<dim3(6144), dim3(256), 0, stream>>>(feat2, rois, pool);
  gemmB_kernel<<<dim3(192), dim3(512), 0, stream>>>(pool, 1024, fc0T, fc0_b, cat, 512, 0, 10);
  embgemm_kernel<<<dim3(192), dim3(512), 0, stream>>>(src_coor, fc0c_w, fc0c_b, fc1cT, fc1c_b, cat);
  gemmB_kernel<<<dim3(192), dim3(512), 0, stream>>>(cat, 512, redT, red_b, obj, 256, 0, 9);
  for (int j = 0; j < 8; j++) {
    internet_mfma<<<dim3(128), dim3(512), 0, stream>>>(j, obj, sbuf, src_coor, out, rbuf, cs,
        b1h, b1l, bafh, bafl, bouh, boul, g_self_b, g_rel_b, g_aff_b, g_out_b, dec_w, dec_b);
    agg4_kernel<<<dim3(256), dim3(512), 0, stream>>>(j, cs, aggT, agg_b, sbuf);
  }
  dec_last<<<dim3(64), dim3(384), 0, stream>>>(sbuf, dec_w, dec_b, out);
  (void)in_sizes; (void)n_in; (void)out_size; (void)ws_size;
}